// Round 1
// baseline (4773.901 us; speedup 1.0000x reference)
//
#include <hip/hip_runtime.h>
#include <math.h>

#define B_ 4
#define T_ 2048
#define C_ 768
#define H_ 12
#define D_ 64
#define N3C (3*C_)

// ---------------- Kernel 1: qkv = x @ W + b, scattered to Q/K/V [B,H,T,D] ----------------
__global__ __launch_bounds__(256) void qkv_gemm(const float* __restrict__ x,
                                                const float* __restrict__ W,
                                                const float* __restrict__ bias,
                                                float* __restrict__ Qo,
                                                float* __restrict__ Ko,
                                                float* __restrict__ Vo)
{
    const int BM = 64, BN = 64, BK = 16;
    __shared__ float As[BK][BM + 1];   // A^T tile, padded vs bank conflicts
    __shared__ float Bs[BK][BN];

    int tid  = threadIdx.x;
    int row0 = blockIdx.y * BM;        // M = B*T = 8192
    int col0 = blockIdx.x * BN;        // N = 2304

    int ty = tid >> 4, tx = tid & 15;  // 16x16 threads, each 4x4 outputs
    int ar = tid >> 2, ak4 = (tid & 3) * 4;   // A-tile load: row, k-quad
    int br = tid >> 4, bc4 = (tid & 15) * 4;  // B-tile load: k-row, col-quad

    float acc[4][4] = {};

    for (int k0 = 0; k0 < C_; k0 += BK) {
        float4 av = *reinterpret_cast<const float4*>(&x[(long)(row0 + ar) * C_ + k0 + ak4]);
        As[ak4 + 0][ar] = av.x;
        As[ak4 + 1][ar] = av.y;
        As[ak4 + 2][ar] = av.z;
        As[ak4 + 3][ar] = av.w;
        float4 bv = *reinterpret_cast<const float4*>(&W[(long)(k0 + br) * N3C + col0 + bc4]);
        *reinterpret_cast<float4*>(&Bs[br][bc4]) = bv;
        __syncthreads();

        #pragma unroll
        for (int k = 0; k < BK; ++k) {
            float a[4], b[4];
            #pragma unroll
            for (int i = 0; i < 4; ++i) a[i] = As[k][ty * 4 + i];
            #pragma unroll
            for (int j = 0; j < 4; ++j) b[j] = Bs[k][tx * 4 + j];
            #pragma unroll
            for (int i = 0; i < 4; ++i)
                #pragma unroll
                for (int j = 0; j < 4; ++j)
                    acc[i][j] = fmaf(a[i], b[j], acc[i][j]);
        }
        __syncthreads();
    }

    // col tile (64 wide, 64-aligned) lies entirely in one of q/k/v and one head
    int p = col0 / C_;                 // 0=q 1=k 2=v
    int h = (col0 % C_) / D_;
    float* dst = (p == 0) ? Qo : (p == 1) ? Ko : Vo;

    #pragma unroll
    for (int i = 0; i < 4; ++i) {
        int r  = row0 + ty * 4 + i;    // global row = b*T + t
        int b_ = r >> 11;              // T = 2048
        int t_ = r & (T_ - 1);
        long idx = (((long)(b_ * H_ + h)) * T_ + t_) * D_ + tx * 4;
        #pragma unroll
        for (int j = 0; j < 4; ++j)
            dst[idx + j] = acc[i][j] + bias[col0 + tx * 4 + j];
    }
}

// ---------------- Kernel 2: causal attention, one block per (b,h,q-row) ----------------
__global__ __launch_bounds__(256) void attn_row(const float* __restrict__ Q,
                                                const float* __restrict__ K,
                                                const float* __restrict__ V,
                                                float* __restrict__ out)
{
    __shared__ float s[T_];            // scores / probs (8 KB)
    __shared__ float qrow[D_];
    __shared__ float red[256];
    __shared__ float yp[4][D_];

    int gid = blockIdx.x;              // (b*H + h)*T + qi
    int qi  = gid & (T_ - 1);
    int bh  = gid >> 11;
    int h   = bh % H_;
    int b   = bh / H_;
    int tid = threadIdx.x;

    const float* Kb = K + (long)bh * T_ * D_;
    const float* Vb = V + (long)bh * T_ * D_;
    const float* qp = Q + ((long)bh * T_ + qi) * D_;

    if (tid < D_) qrow[tid] = qp[tid];
    __syncthreads();

    int nk = qi + 1;

    // scores + local max
    float lmax = -INFINITY;
    for (int k = tid; k < nk; k += 256) {
        const float* kr = Kb + (long)k * D_;
        float dot = 0.f;
        #pragma unroll
        for (int d = 0; d < D_; d += 4) {
            float4 kv = *reinterpret_cast<const float4*>(kr + d);
            dot = fmaf(qrow[d + 0], kv.x, dot);
            dot = fmaf(qrow[d + 1], kv.y, dot);
            dot = fmaf(qrow[d + 2], kv.z, dot);
            dot = fmaf(qrow[d + 3], kv.w, dot);
        }
        dot *= 8.0f;                   // * sqrt(d), faithful to reference
        s[k] = dot;
        lmax = fmaxf(lmax, dot);
    }
    red[tid] = lmax;
    __syncthreads();
    for (int off = 128; off > 0; off >>= 1) {
        if (tid < off) red[tid] = fmaxf(red[tid], red[tid + off]);
        __syncthreads();
    }
    float m = red[0];
    __syncthreads();

    // exp + local sum
    float lsum = 0.f;
    for (int k = tid; k < nk; k += 256) {
        float p = __expf(s[k] - m);
        s[k] = p;
        lsum += p;
    }
    red[tid] = lsum;
    __syncthreads();
    for (int off = 128; off > 0; off >>= 1) {
        if (tid < off) red[tid] += red[tid + off];
        __syncthreads();
    }
    float linv = 1.0f / red[0];
    __syncthreads();

    // PV: wave g handles keys k = g, g+4, ...; lane d accumulates dim d
    int d = tid & 63, g = tid >> 6;
    float acc = 0.f;
    for (int k = g; k < nk; k += 4)
        acc = fmaf(s[k], Vb[(long)k * D_ + d], acc);
    yp[g][d] = acc;
    __syncthreads();

    if (tid < D_) {
        float y = (yp[0][tid] + yp[1][tid] + yp[2][tid] + yp[3][tid]) * linv;
        out[((long)(b * T_ + qi)) * C_ + h * D_ + tid] = y;
    }
}

extern "C" void kernel_launch(void* const* d_in, const int* in_sizes, int n_in,
                              void* d_out, int out_size, void* d_ws, size_t ws_size,
                              hipStream_t stream)
{
    const float* x    = (const float*)d_in[0];
    const float* W    = (const float*)d_in[1];
    const float* bias = (const float*)d_in[2];
    float* out = (float*)d_out;

    // workspace layout: Q | K | V, each B*H*T*D floats (25.17 MB each, 75.5 MB total)
    const long per = (long)B_ * H_ * T_ * D_;
    float* Qw = (float*)d_ws;
    float* Kw = Qw + per;
    float* Vw = Kw + per;

    dim3 ggrid(N3C / 64, (B_ * T_) / 64);   // 36 x 128
    qkv_gemm<<<ggrid, 256, 0, stream>>>(x, W, bias, Qw, Kw, Vw);

    dim3 agrid(B_ * H_ * T_);               // 98304 blocks
    attn_row<<<agrid, 256, 0, stream>>>(Qw, Kw, Vw, out);
}

// Round 2
// 314.796 us; speedup vs baseline: 15.1651x; 15.1651x over previous
//
#include <hip/hip_runtime.h>
#include <math.h>

#define B_ 4
#define T_ 2048
#define C_ 768
#define H_ 12
#define D_ 64
#define N3C (3*C_)
#define BH_ (B_*H_)

typedef float f32x4 __attribute__((ext_vector_type(4)));
typedef short bf16x8 __attribute__((ext_vector_type(8)));
typedef short short4v __attribute__((ext_vector_type(4)));
typedef unsigned short ushort_t;

__device__ __forceinline__ unsigned short f2bf(float x) {
    unsigned int u = __float_as_uint(x);
    u += 0x7FFFu + ((u >> 16) & 1u);
    return (unsigned short)(u >> 16);
}
__device__ __forceinline__ float bf2f(unsigned short h) {
    return __uint_as_float(((unsigned int)h) << 16);
}

// ---------------- Kernel 0: Wt[n][k] = W[k][n] (fp32) ----------------
__global__ __launch_bounds__(256) void transpose_w(const float* __restrict__ W,
                                                   float* __restrict__ Wt)
{
    __shared__ float tile[64][65];
    int n0 = blockIdx.x * 64, k0 = blockIdx.y * 64;
    int tid = threadIdx.x;
    #pragma unroll
    for (int t = 0; t < 16; ++t) {
        int c = t * 256 + tid;
        int kr = c >> 6, nc = c & 63;
        tile[kr][nc] = W[(size_t)(k0 + kr) * N3C + n0 + nc];
    }
    __syncthreads();
    #pragma unroll
    for (int t = 0; t < 16; ++t) {
        int c = t * 256 + tid;
        int nr = c >> 6, kc = c & 63;
        Wt[(size_t)(n0 + nr) * C_ + k0 + kc] = tile[kc][nr];
    }
}

// ---------------- Kernel 1: qkv = x @ W + b via split-bf16 MFMA ----------------
// BM=128 BN=128 BK=32, 4 waves (2x2), each wave 64x64 (4x4 MFMA tiles).
// Epilogue: Q (x8) -> Qh/Ql split bf16 [bh][t][d]; K -> Kh/Kl; V -> Vt[bh][d][t] bf16.
__global__ __launch_bounds__(256) void qkv_gemm(const float* __restrict__ x,
                                                const float* __restrict__ Wt,
                                                const float* __restrict__ bias,
                                                ushort_t* __restrict__ Qh,
                                                ushort_t* __restrict__ Ql,
                                                ushort_t* __restrict__ Kh,
                                                ushort_t* __restrict__ Kl,
                                                ushort_t* __restrict__ Vt)
{
    __shared__ __align__(16) ushort_t Ah[128 * 40];
    __shared__ __align__(16) ushort_t Al[128 * 40];
    __shared__ __align__(16) ushort_t Bh[128 * 40];
    __shared__ __align__(16) ushort_t Bl[128 * 40];

    int tid  = threadIdx.x;
    int lane = tid & 63, w = tid >> 6;
    int wm = w >> 1, wn = w & 1;
    int l15 = lane & 15, l4 = lane >> 4;
    int row0 = blockIdx.y * 128;          // M = 8192
    int col0 = blockIdx.x * 128;          // N = 2304

    f32x4 acc[4][4];
    #pragma unroll
    for (int i = 0; i < 4; ++i)
        #pragma unroll
        for (int j = 0; j < 4; ++j)
            acc[i][j] = f32x4{0.f, 0.f, 0.f, 0.f};

    for (int k0 = 0; k0 < C_; k0 += 32) {
        __syncthreads();
        // stage A (x rows) and B (Wt rows), splitting fp32 -> hi/lo bf16
        #pragma unroll
        for (int t = 0; t < 4; ++t) {
            int c = t * 256 + tid;
            int m = c >> 3, kq = (c & 7) * 4;
            float4 av = *reinterpret_cast<const float4*>(&x[(size_t)(row0 + m) * C_ + k0 + kq]);
            unsigned short h0 = f2bf(av.x), h1 = f2bf(av.y), h2 = f2bf(av.z), h3 = f2bf(av.w);
            short4v hv = {(short)h0, (short)h1, (short)h2, (short)h3};
            short4v lv = {(short)f2bf(av.x - bf2f(h0)), (short)f2bf(av.y - bf2f(h1)),
                          (short)f2bf(av.z - bf2f(h2)), (short)f2bf(av.w - bf2f(h3))};
            *reinterpret_cast<short4v*>(&Ah[m * 40 + kq]) = hv;
            *reinterpret_cast<short4v*>(&Al[m * 40 + kq]) = lv;

            float4 bv = *reinterpret_cast<const float4*>(&Wt[(size_t)(col0 + m) * C_ + k0 + kq]);
            unsigned short g0 = f2bf(bv.x), g1 = f2bf(bv.y), g2 = f2bf(bv.z), g3 = f2bf(bv.w);
            short4v hw = {(short)g0, (short)g1, (short)g2, (short)g3};
            short4v lw = {(short)f2bf(bv.x - bf2f(g0)), (short)f2bf(bv.y - bf2f(g1)),
                          (short)f2bf(bv.z - bf2f(g2)), (short)f2bf(bv.w - bf2f(g3))};
            *reinterpret_cast<short4v*>(&Bh[m * 40 + kq]) = hw;
            *reinterpret_cast<short4v*>(&Bl[m * 40 + kq]) = lw;
        }
        __syncthreads();

        bf16x8 a_h[4], a_l[4], b_h[4], b_l[4];
        #pragma unroll
        for (int mt = 0; mt < 4; ++mt) {
            int r = wm * 64 + mt * 16 + l15;
            a_h[mt] = *reinterpret_cast<const bf16x8*>(&Ah[r * 40 + l4 * 8]);
            a_l[mt] = *reinterpret_cast<const bf16x8*>(&Al[r * 40 + l4 * 8]);
        }
        #pragma unroll
        for (int nt = 0; nt < 4; ++nt) {
            int r = wn * 64 + nt * 16 + l15;
            b_h[nt] = *reinterpret_cast<const bf16x8*>(&Bh[r * 40 + l4 * 8]);
            b_l[nt] = *reinterpret_cast<const bf16x8*>(&Bl[r * 40 + l4 * 8]);
        }
        #pragma unroll
        for (int mt = 0; mt < 4; ++mt)
            #pragma unroll
            for (int nt = 0; nt < 4; ++nt) {
                acc[mt][nt] = __builtin_amdgcn_mfma_f32_16x16x32_bf16(a_h[mt], b_h[nt], acc[mt][nt], 0, 0, 0);
                acc[mt][nt] = __builtin_amdgcn_mfma_f32_16x16x32_bf16(a_h[mt], b_l[nt], acc[mt][nt], 0, 0, 0);
                acc[mt][nt] = __builtin_amdgcn_mfma_f32_16x16x32_bf16(a_l[mt], b_h[nt], acc[mt][nt], 0, 0, 0);
            }
    }

    // epilogue: D layout col = l15 (n), row = l4*4 + r (m)
    #pragma unroll
    for (int nt = 0; nt < 4; ++nt) {
        int gcol = col0 + wn * 64 + nt * 16 + l15;
        int p    = gcol / C_;
        int rem  = gcol - p * C_;
        int h    = rem >> 6, d = rem & 63;
        float bv = bias[gcol];
        #pragma unroll
        for (int mt = 0; mt < 4; ++mt) {
            #pragma unroll
            for (int r = 0; r < 4; ++r) {
                int grow = row0 + wm * 64 + mt * 16 + l4 * 4 + r;
                int b = grow >> 11, t = grow & (T_ - 1);
                int bh = b * H_ + h;
                float v = acc[mt][nt][r] + bv;
                if (p == 0) {
                    float v8 = v * 8.0f;            // fold * sqrt(d) into Q
                    unsigned short hi = f2bf(v8);
                    size_t idx = ((size_t)bh * T_ + t) * D_ + d;
                    Qh[idx] = hi;
                    Ql[idx] = f2bf(v8 - bf2f(hi));
                } else if (p == 1) {
                    unsigned short hi = f2bf(v);
                    size_t idx = ((size_t)bh * T_ + t) * D_ + d;
                    Kh[idx] = hi;
                    Kl[idx] = f2bf(v - bf2f(hi));
                } else {
                    Vt[((size_t)bh * D_ + d) * T_ + t] = f2bf(v);  // transposed store
                }
            }
        }
    }
}

// ---------------- Kernel 2: flash attention, MFMA, split-bf16 QK^T ----------------
// Block: 4 waves, 64 q-rows (wave w owns rows q0+16w..+16). K-tile = 64 keys.
__global__ __launch_bounds__(256) void attn(const ushort_t* __restrict__ Qh,
                                            const ushort_t* __restrict__ Ql,
                                            const ushort_t* __restrict__ Kh,
                                            const ushort_t* __restrict__ Kl,
                                            const ushort_t* __restrict__ Vt,
                                            float* __restrict__ out)
{
    __shared__ __align__(16) ushort_t Khs[64 * 72];
    __shared__ __align__(16) ushort_t Kls[64 * 72];
    __shared__ __align__(16) ushort_t Vts[64 * 72];   // [d][k]
    __shared__ __align__(16) ushort_t Ps[4][16 * 72]; // per-wave P [q][k]

    int tid = threadIdx.x, lane = tid & 63, w = tid >> 6;
    int l15 = lane & 15, l4 = lane >> 4;
    int bid = blockIdx.x;
    int qt = 31 - bid / BH_;              // longest tiles scheduled first
    int bh = bid % BH_;
    int b = bh / H_, h = bh % H_;
    int q0 = qt * 64;

    // Q fragments (held in registers for whole block)
    int qrow = q0 + w * 16 + l15;
    const ushort_t* qbh = Qh + ((size_t)bh * T_ + qrow) * D_;
    const ushort_t* qbl = Ql + ((size_t)bh * T_ + qrow) * D_;
    bf16x8 qh[2], ql[2];
    qh[0] = *reinterpret_cast<const bf16x8*>(&qbh[l4 * 8]);
    qh[1] = *reinterpret_cast<const bf16x8*>(&qbh[32 + l4 * 8]);
    ql[0] = *reinterpret_cast<const bf16x8*>(&qbl[l4 * 8]);
    ql[1] = *reinterpret_cast<const bf16x8*>(&qbl[32 + l4 * 8]);

    f32x4 yacc[4];
    #pragma unroll
    for (int i = 0; i < 4; ++i) yacc[i] = f32x4{0.f, 0.f, 0.f, 0.f};
    float m_run[4] = {-INFINITY, -INFINITY, -INFINITY, -INFINITY};
    float l_run[4] = {0.f, 0.f, 0.f, 0.f};

    int ntile = qt + 1;
    for (int it = 0; it < ntile; ++it) {
        int k0 = it * 64;
        __syncthreads();
        // stage K hi/lo rows and Vt rows (all coalesced 8B chunks)
        #pragma unroll
        for (int t = 0; t < 4; ++t) {
            int c = t * 256 + tid;
            int r = c >> 4, cq = (c & 15) * 4;
            *reinterpret_cast<short4v*>(&Khs[r * 72 + cq]) =
                *reinterpret_cast<const short4v*>(&Kh[((size_t)bh * T_ + k0 + r) * D_ + cq]);
            *reinterpret_cast<short4v*>(&Kls[r * 72 + cq]) =
                *reinterpret_cast<const short4v*>(&Kl[((size_t)bh * T_ + k0 + r) * D_ + cq]);
            *reinterpret_cast<short4v*>(&Vts[r * 72 + cq]) =
                *reinterpret_cast<const short4v*>(&Vt[((size_t)bh * D_ + r) * T_ + k0 + cq]);
        }
        __syncthreads();

        // QK^T: S[q][k], 4 k-subtiles, K-dim 64 = 2 halves, 3-term split
        f32x4 sa[4];
        #pragma unroll
        for (int i = 0; i < 4; ++i) sa[i] = f32x4{0.f, 0.f, 0.f, 0.f};
        #pragma unroll
        for (int kt = 0; kt < 4; ++kt) {
            int krow = kt * 16 + l15;
            #pragma unroll
            for (int dh = 0; dh < 2; ++dh) {
                bf16x8 kh = *reinterpret_cast<const bf16x8*>(&Khs[krow * 72 + dh * 32 + l4 * 8]);
                bf16x8 kl = *reinterpret_cast<const bf16x8*>(&Kls[krow * 72 + dh * 32 + l4 * 8]);
                sa[kt] = __builtin_amdgcn_mfma_f32_16x16x32_bf16(qh[dh], kh, sa[kt], 0, 0, 0);
                sa[kt] = __builtin_amdgcn_mfma_f32_16x16x32_bf16(qh[dh], kl, sa[kt], 0, 0, 0);
                sa[kt] = __builtin_amdgcn_mfma_f32_16x16x32_bf16(ql[dh], kh, sa[kt], 0, 0, 0);
            }
        }

        // causal mask (only the diagonal tile needs it)
        if (it == ntile - 1) {
            #pragma unroll
            for (int kt = 0; kt < 4; ++kt)
                #pragma unroll
                for (int r = 0; r < 4; ++r) {
                    int kg = k0 + kt * 16 + l15;
                    int qg = q0 + w * 16 + l4 * 4 + r;
                    if (kg > qg) sa[kt][r] = -INFINITY;
                }
        }

        // online softmax: row = q = l4*4+r, cols spread over l15 lanes x 4 subtiles
        float p[4][4];   // [kt][r]
        float sc[4];
        #pragma unroll
        for (int r = 0; r < 4; ++r) {
            float mx = fmaxf(fmaxf(sa[0][r], sa[1][r]), fmaxf(sa[2][r], sa[3][r]));
            mx = fmaxf(mx, __shfl_xor(mx, 1));
            mx = fmaxf(mx, __shfl_xor(mx, 2));
            mx = fmaxf(mx, __shfl_xor(mx, 4));
            mx = fmaxf(mx, __shfl_xor(mx, 8));
            float mn = fmaxf(m_run[r], mx);
            sc[r] = __expf(m_run[r] - mn);
            m_run[r] = mn;
            float rs = 0.f;
            #pragma unroll
            for (int kt = 0; kt < 4; ++kt) {
                p[kt][r] = __expf(sa[kt][r] - mn);
                rs += p[kt][r];
            }
            rs += __shfl_xor(rs, 1);
            rs += __shfl_xor(rs, 2);
            rs += __shfl_xor(rs, 4);
            rs += __shfl_xor(rs, 8);
            l_run[r] = l_run[r] * sc[r] + rs;
        }
        #pragma unroll
        for (int dt = 0; dt < 4; ++dt)
            #pragma unroll
            for (int r = 0; r < 4; ++r)
                yacc[dt][r] *= sc[r];

        // P -> per-wave LDS (bf16), then PV
        ushort_t* pw = &Ps[w][0];
        #pragma unroll
        for (int kt = 0; kt < 4; ++kt)
            #pragma unroll
            for (int r = 0; r < 4; ++r)
                pw[(l4 * 4 + r) * 72 + kt * 16 + l15] = f2bf(p[kt][r]);

        bf16x8 pa[2];
        pa[0] = *reinterpret_cast<const bf16x8*>(&pw[l15 * 72 + l4 * 8]);
        pa[1] = *reinterpret_cast<const bf16x8*>(&pw[l15 * 72 + 32 + l4 * 8]);
        #pragma unroll
        for (int dt = 0; dt < 4; ++dt) {
            #pragma unroll
            for (int kh2 = 0; kh2 < 2; ++kh2) {
                bf16x8 vb = *reinterpret_cast<const bf16x8*>(&Vts[(dt * 16 + l15) * 72 + kh2 * 32 + l4 * 8]);
                yacc[dt] = __builtin_amdgcn_mfma_f32_16x16x32_bf16(pa[kh2], vb, yacc[dt], 0, 0, 0);
            }
        }
    }

    // epilogue: y = yacc / l_run ; out[b][t][h*64 + d]
    #pragma unroll
    for (int r = 0; r < 4; ++r) {
        float inv = 1.0f / l_run[r];
        int qg = q0 + w * 16 + l4 * 4 + r;
        size_t base = ((size_t)(b * T_ + qg)) * C_ + h * D_;
        #pragma unroll
        for (int dt = 0; dt < 4; ++dt)
            out[base + dt * 16 + l15] = yacc[dt][r] * inv;
    }
}

extern "C" void kernel_launch(void* const* d_in, const int* in_sizes, int n_in,
                              void* d_out, int out_size, void* d_ws, size_t ws_size,
                              hipStream_t stream)
{
    const float* x    = (const float*)d_in[0];
    const float* W    = (const float*)d_in[1];
    const float* bias = (const float*)d_in[2];

    const size_t per = (size_t)BH_ * T_ * D_;   // 6291456 elements
    ushort_t* Qh = (ushort_t*)d_ws;
    ushort_t* Ql = Qh + per;
    ushort_t* Kh = Ql + per;
    ushort_t* Kl = Kh + per;
    ushort_t* Vt = Kl + per;
    float*    Wt = (float*)(Vt + per);          // 62914560 B offset, 16B aligned

    transpose_w<<<dim3(N3C / 64, C_ / 64), 256, 0, stream>>>(W, Wt);
    qkv_gemm<<<dim3(N3C / 128, (B_ * T_) / 128), 256, 0, stream>>>(x, Wt, bias, Qh, Ql, Kh, Kl, Vt);
    attn<<<dim3(BH_ * (T_ / 64)), 256, 0, stream>>>(Qh, Ql, Kh, Kl, Vt, (float*)d_out);
}

// Round 3
// 292.813 us; speedup vs baseline: 16.3036x; 1.0751x over previous
//
#include <hip/hip_runtime.h>
#include <math.h>

#define B_ 4
#define T_ 2048
#define C_ 768
#define H_ 12
#define D_ 64
#define N3C (3*C_)
#define BH_ (B_*H_)
#define KSPLIT 1536   // [hi | lo] concatenated K for split operands

typedef float f32x4 __attribute__((ext_vector_type(4)));
typedef short bf16x8 __attribute__((ext_vector_type(8)));
typedef short short4v __attribute__((ext_vector_type(4)));
typedef unsigned short ushort_t;

__device__ __forceinline__ unsigned short f2bf(float x) {
    unsigned int u = __float_as_uint(x);
    u += 0x7FFFu + ((u >> 16) & 1u);
    return (unsigned short)(u >> 16);
}
__device__ __forceinline__ float bf2f(unsigned short h) {
    return __uint_as_float(((unsigned int)h) << 16);
}
__device__ __forceinline__ void async16(const ushort_t* g, ushort_t* l) {
    __builtin_amdgcn_global_load_lds(
        (const __attribute__((address_space(1))) unsigned int*)(g),
        (__attribute__((address_space(3))) unsigned int*)(l),
        16, 0, 0);
}

// ---------------- Kernel 0a: Xs[m][0:768]=hi(x), [768:1536]=lo(x) ----------------
__global__ __launch_bounds__(256) void split_x(const float* __restrict__ x,
                                               ushort_t* __restrict__ Xs)
{
    int idx = blockIdx.x * 256 + threadIdx.x;     // 8192*768/4 quads
    int row = idx / 192;
    int col = (idx - row * 192) * 4;
    float4 v = *reinterpret_cast<const float4*>(&x[(size_t)row * C_ + col]);
    unsigned short h0 = f2bf(v.x), h1 = f2bf(v.y), h2 = f2bf(v.z), h3 = f2bf(v.w);
    short4v hv = {(short)h0, (short)h1, (short)h2, (short)h3};
    short4v lv = {(short)f2bf(v.x - bf2f(h0)), (short)f2bf(v.y - bf2f(h1)),
                  (short)f2bf(v.z - bf2f(h2)), (short)f2bf(v.w - bf2f(h3))};
    *reinterpret_cast<short4v*>(&Xs[(size_t)row * KSPLIT + col]) = hv;
    *reinterpret_cast<short4v*>(&Xs[(size_t)row * KSPLIT + 768 + col]) = lv;
}

// ---------------- Kernel 0b: Ws[n][0:768]=hi(W[k][n]) , [768:1536]=lo ----------------
__global__ __launch_bounds__(256) void split_w(const float* __restrict__ W,
                                               ushort_t* __restrict__ Ws)
{
    __shared__ float tile[64][65];
    int n0 = blockIdx.x * 64, k0 = blockIdx.y * 64;
    int tid = threadIdx.x;
    #pragma unroll
    for (int t = 0; t < 16; ++t) {
        int c = t * 256 + tid;
        int kr = c >> 6, nc = c & 63;
        tile[kr][nc] = W[(size_t)(k0 + kr) * N3C + n0 + nc];
    }
    __syncthreads();
    #pragma unroll
    for (int t = 0; t < 16; ++t) {
        int c = t * 256 + tid;
        int nr = c >> 6, kc = c & 63;
        float v = tile[kc][nr];
        unsigned short h = f2bf(v);
        Ws[(size_t)(n0 + nr) * KSPLIT + k0 + kc] = h;
        Ws[(size_t)(n0 + nr) * KSPLIT + 768 + k0 + kc] = f2bf(v - bf2f(h));
    }
}

// ---------------- Kernel 1: qkv GEMM, plain bf16 MFMA over concatenated K ----------------
// A segs over k: [Ah | Al | Ah]  (map: k<1536 -> k, else k-1536)
// B segs over k: [Bh | Bh | Bl]  (map: k<768  -> k, else k-768)
// V columns (col0>=1536) need only the hi*hi term -> kmax=768.
__global__ __launch_bounds__(256) void qkv_gemm(const ushort_t* __restrict__ Xs,
                                                const ushort_t* __restrict__ Ws,
                                                const float* __restrict__ bias,
                                                ushort_t* __restrict__ Qh,
                                                ushort_t* __restrict__ Ql,
                                                ushort_t* __restrict__ Kh,
                                                ushort_t* __restrict__ Kl,
                                                ushort_t* __restrict__ Vt)
{
    __shared__ __align__(16) ushort_t As[128 * 64];   // [m][k] linear (global_load_lds)
    __shared__ __align__(16) ushort_t Bs[128 * 64];   // [n][k] linear

    int tid = threadIdx.x, lane = tid & 63, w = tid >> 6;
    int wm = w >> 1, wn = w & 1;
    int l15 = lane & 15, l4 = lane >> 4;
    int lrow = lane >> 3, lcol = (lane & 7) * 8;

    // XCD-chunked bijective swizzle (nwg=1152, 1152%8==0); 18 consecutive logical
    // blocks share one A panel.
    int wg = blockIdx.x;
    int l = (wg & 7) * 144 + (wg >> 3);
    int mt = l / 18, nt = l % 18;
    int row0 = mt * 128, col0 = nt * 128;
    int kmax = (col0 >= 1536) ? 768 : 2304;

    f32x4 acc[4][4];
    #pragma unroll
    for (int i = 0; i < 4; ++i)
        #pragma unroll
        for (int j = 0; j < 4; ++j)
            acc[i][j] = f32x4{0.f, 0.f, 0.f, 0.f};

    for (int k0 = 0; k0 < kmax; k0 += 64) {
        int ka = (k0 < 1536) ? k0 : k0 - 1536;
        int kb = (k0 < 768) ? k0 : k0 - 768;
        __syncthreads();
        const ushort_t* gA = Xs + (size_t)(row0 + w * 32 + lrow) * KSPLIT + ka + lcol;
        const ushort_t* gB = Ws + (size_t)(col0 + w * 32 + lrow) * KSPLIT + kb + lcol;
        #pragma unroll
        for (int j = 0; j < 4; ++j) {
            async16(gA + (size_t)j * 8 * KSPLIT, &As[(w * 32 + j * 8) * 64]);
            async16(gB + (size_t)j * 8 * KSPLIT, &Bs[(w * 32 + j * 8) * 64]);
        }
        __syncthreads();   // compiler drains vmcnt before barrier

        #pragma unroll
        for (int kk = 0; kk < 2; ++kk) {
            bf16x8 af[4], bfr[4];
            #pragma unroll
            for (int m = 0; m < 4; ++m)
                af[m] = *reinterpret_cast<const bf16x8*>(&As[(wm * 64 + m * 16 + l15) * 64 + kk * 32 + l4 * 8]);
            #pragma unroll
            for (int n = 0; n < 4; ++n)
                bfr[n] = *reinterpret_cast<const bf16x8*>(&Bs[(wn * 64 + n * 16 + l15) * 64 + kk * 32 + l4 * 8]);
            #pragma unroll
            for (int m = 0; m < 4; ++m)
                #pragma unroll
                for (int n = 0; n < 4; ++n)
                    acc[m][n] = __builtin_amdgcn_mfma_f32_16x16x32_bf16(af[m], bfr[n], acc[m][n], 0, 0, 0);
        }
    }

    // epilogue: col = l15 (n), row = l4*4 + r (m)
    #pragma unroll
    for (int n = 0; n < 4; ++n) {
        int gcol = col0 + wn * 64 + n * 16 + l15;
        int p    = gcol / C_;
        int rem  = gcol - p * C_;
        int h    = rem >> 6, d = rem & 63;
        float bv = bias[gcol];
        #pragma unroll
        for (int m = 0; m < 4; ++m) {
            #pragma unroll
            for (int r = 0; r < 4; ++r) {
                int grow = row0 + wm * 64 + m * 16 + l4 * 4 + r;
                int b = grow >> 11, t = grow & (T_ - 1);
                int bh = b * H_ + h;
                float v = acc[m][n][r] + bv;
                if (p == 0) {
                    float v8 = v * 8.0f;            // fold * sqrt(d) into Q
                    unsigned short hi = f2bf(v8);
                    size_t idx = ((size_t)bh * T_ + t) * D_ + d;
                    Qh[idx] = hi;
                    Ql[idx] = f2bf(v8 - bf2f(hi));
                } else if (p == 1) {
                    unsigned short hi = f2bf(v);
                    size_t idx = ((size_t)bh * T_ + t) * D_ + d;
                    Kh[idx] = hi;
                    Kl[idx] = f2bf(v - bf2f(hi));
                } else {
                    Vt[((size_t)bh * D_ + d) * T_ + t] = f2bf(v);  // transposed store
                }
            }
        }
    }
}

// ---------------- Kernel 2: flash attention, MFMA, split-bf16 QK^T ----------------
__global__ __launch_bounds__(256) void attn(const ushort_t* __restrict__ Qh,
                                            const ushort_t* __restrict__ Ql,
                                            const ushort_t* __restrict__ Kh,
                                            const ushort_t* __restrict__ Kl,
                                            const ushort_t* __restrict__ Vt,
                                            float* __restrict__ out)
{
    __shared__ __align__(16) ushort_t Khs[64 * 72];
    __shared__ __align__(16) ushort_t Kls[64 * 72];
    __shared__ __align__(16) ushort_t Vts[64 * 72];   // [d][k]
    __shared__ __align__(16) ushort_t Ps[4][16 * 72]; // per-wave P [q][k]

    int tid = threadIdx.x, lane = tid & 63, w = tid >> 6;
    int l15 = lane & 15, l4 = lane >> 4;
    int bid = blockIdx.x;
    int qt = 31 - bid / BH_;              // longest tiles scheduled first
    int bh = bid % BH_;
    int b = bh / H_, h = bh % H_;
    int q0 = qt * 64;

    int qrow = q0 + w * 16 + l15;
    const ushort_t* qbh = Qh + ((size_t)bh * T_ + qrow) * D_;
    const ushort_t* qbl = Ql + ((size_t)bh * T_ + qrow) * D_;
    bf16x8 qh[2], ql[2];
    qh[0] = *reinterpret_cast<const bf16x8*>(&qbh[l4 * 8]);
    qh[1] = *reinterpret_cast<const bf16x8*>(&qbh[32 + l4 * 8]);
    ql[0] = *reinterpret_cast<const bf16x8*>(&qbl[l4 * 8]);
    ql[1] = *reinterpret_cast<const bf16x8*>(&qbl[32 + l4 * 8]);

    f32x4 yacc[4];
    #pragma unroll
    for (int i = 0; i < 4; ++i) yacc[i] = f32x4{0.f, 0.f, 0.f, 0.f};
    float m_run[4] = {-INFINITY, -INFINITY, -INFINITY, -INFINITY};
    float l_run[4] = {0.f, 0.f, 0.f, 0.f};

    int ntile = qt + 1;
    for (int it = 0; it < ntile; ++it) {
        int k0 = it * 64;
        __syncthreads();
        #pragma unroll
        for (int t = 0; t < 4; ++t) {
            int c = t * 256 + tid;
            int r = c >> 4, cq = (c & 15) * 4;
            *reinterpret_cast<short4v*>(&Khs[r * 72 + cq]) =
                *reinterpret_cast<const short4v*>(&Kh[((size_t)bh * T_ + k0 + r) * D_ + cq]);
            *reinterpret_cast<short4v*>(&Kls[r * 72 + cq]) =
                *reinterpret_cast<const short4v*>(&Kl[((size_t)bh * T_ + k0 + r) * D_ + cq]);
            *reinterpret_cast<short4v*>(&Vts[r * 72 + cq]) =
                *reinterpret_cast<const short4v*>(&Vt[((size_t)bh * D_ + r) * T_ + k0 + cq]);
        }
        __syncthreads();

        f32x4 sa[4];
        #pragma unroll
        for (int i = 0; i < 4; ++i) sa[i] = f32x4{0.f, 0.f, 0.f, 0.f};
        #pragma unroll
        for (int kt = 0; kt < 4; ++kt) {
            int krow = kt * 16 + l15;
            #pragma unroll
            for (int dh = 0; dh < 2; ++dh) {
                bf16x8 kh = *reinterpret_cast<const bf16x8*>(&Khs[krow * 72 + dh * 32 + l4 * 8]);
                bf16x8 kl = *reinterpret_cast<const bf16x8*>(&Kls[krow * 72 + dh * 32 + l4 * 8]);
                sa[kt] = __builtin_amdgcn_mfma_f32_16x16x32_bf16(qh[dh], kh, sa[kt], 0, 0, 0);
                sa[kt] = __builtin_amdgcn_mfma_f32_16x16x32_bf16(qh[dh], kl, sa[kt], 0, 0, 0);
                sa[kt] = __builtin_amdgcn_mfma_f32_16x16x32_bf16(ql[dh], kh, sa[kt], 0, 0, 0);
            }
        }

        if (it == ntile - 1) {
            #pragma unroll
            for (int kt = 0; kt < 4; ++kt)
                #pragma unroll
                for (int r = 0; r < 4; ++r) {
                    int kg = k0 + kt * 16 + l15;
                    int qg = q0 + w * 16 + l4 * 4 + r;
                    if (kg > qg) sa[kt][r] = -INFINITY;
                }
        }

        float p[4][4];
        float sc[4];
        #pragma unroll
        for (int r = 0; r < 4; ++r) {
            float mx = fmaxf(fmaxf(sa[0][r], sa[1][r]), fmaxf(sa[2][r], sa[3][r]));
            mx = fmaxf(mx, __shfl_xor(mx, 1));
            mx = fmaxf(mx, __shfl_xor(mx, 2));
            mx = fmaxf(mx, __shfl_xor(mx, 4));
            mx = fmaxf(mx, __shfl_xor(mx, 8));
            float mn = fmaxf(m_run[r], mx);
            sc[r] = __expf(m_run[r] - mn);
            m_run[r] = mn;
            float rs = 0.f;
            #pragma unroll
            for (int kt = 0; kt < 4; ++kt) {
                p[kt][r] = __expf(sa[kt][r] - mn);
                rs += p[kt][r];
            }
            rs += __shfl_xor(rs, 1);
            rs += __shfl_xor(rs, 2);
            rs += __shfl_xor(rs, 4);
            rs += __shfl_xor(rs, 8);
            l_run[r] = l_run[r] * sc[r] + rs;
        }
        #pragma unroll
        for (int dt = 0; dt < 4; ++dt)
            #pragma unroll
            for (int r = 0; r < 4; ++r)
                yacc[dt][r] *= sc[r];

        ushort_t* pw = &Ps[w][0];
        #pragma unroll
        for (int kt = 0; kt < 4; ++kt)
            #pragma unroll
            for (int r = 0; r < 4; ++r)
                pw[(l4 * 4 + r) * 72 + kt * 16 + l15] = f2bf(p[kt][r]);

        bf16x8 pa[2];
        pa[0] = *reinterpret_cast<const bf16x8*>(&pw[l15 * 72 + l4 * 8]);
        pa[1] = *reinterpret_cast<const bf16x8*>(&pw[l15 * 72 + 32 + l4 * 8]);
        #pragma unroll
        for (int dt = 0; dt < 4; ++dt) {
            #pragma unroll
            for (int kh2 = 0; kh2 < 2; ++kh2) {
                bf16x8 vb = *reinterpret_cast<const bf16x8*>(&Vts[(dt * 16 + l15) * 72 + kh2 * 32 + l4 * 8]);
                yacc[dt] = __builtin_amdgcn_mfma_f32_16x16x32_bf16(pa[kh2], vb, yacc[dt], 0, 0, 0);
            }
        }
    }

    #pragma unroll
    for (int r = 0; r < 4; ++r) {
        float inv = 1.0f / l_run[r];
        int qg = q0 + w * 16 + l4 * 4 + r;
        size_t base = ((size_t)(b * T_ + qg)) * C_ + h * D_;
        #pragma unroll
        for (int dt = 0; dt < 4; ++dt)
            out[base + dt * 16 + l15] = yacc[dt][r] * inv;
    }
}

extern "C" void kernel_launch(void* const* d_in, const int* in_sizes, int n_in,
                              void* d_out, int out_size, void* d_ws, size_t ws_size,
                              hipStream_t stream)
{
    const float* x    = (const float*)d_in[0];
    const float* W    = (const float*)d_in[1];
    const float* bias = (const float*)d_in[2];

    const size_t per = (size_t)BH_ * T_ * D_;       // 6291456
    ushort_t* Qh = (ushort_t*)d_ws;
    ushort_t* Ql = Qh + per;
    ushort_t* Kh = Ql + per;
    ushort_t* Kl = Kh + per;
    ushort_t* Vt = Kl + per;
    ushort_t* Xs = Vt + per;                        // 8192*1536
    ushort_t* Ws = Xs + (size_t)8192 * KSPLIT;      // 2304*1536
    // total ~95.2 MB of d_ws

    split_x<<<dim3((8192 * 768 / 4) / 256), 256, 0, stream>>>(x, Xs);
    split_w<<<dim3(N3C / 64, C_ / 64), 256, 0, stream>>>(W, Ws);
    qkv_gemm<<<dim3(64 * 18), 256, 0, stream>>>(Xs, Ws, bias, Qh, Ql, Kh, Kl, Vt);
    attn<<<dim3(BH_ * (T_ / 64)), 256, 0, stream>>>(Qh, Ql, Kh, Kl, Vt, (float*)d_out);
}

// Round 4
// 230.796 us; speedup vs baseline: 20.6845x; 1.2687x over previous
//
#include <hip/hip_runtime.h>
#include <math.h>

#define B_ 4
#define T_ 2048
#define C_ 768
#define H_ 12
#define D_ 64
#define N3C (3*C_)
#define BH_ (B_*H_)
#define KSPLIT 1536   // [hi | lo] concatenated K for split operands
#define QSCALE 11.5415603f   // 8 * log2(e): fold sqrt(d) and exp->exp2 into Q
#define PPS 72        // P-tile LDS pitch (shorts)

typedef float f32x4 __attribute__((ext_vector_type(4)));
typedef short bf16x8 __attribute__((ext_vector_type(8)));
typedef short short4v __attribute__((ext_vector_type(4)));
typedef unsigned short ushort_t;

__device__ __forceinline__ unsigned short f2bf(float x) {
    unsigned int u = __float_as_uint(x);
    u += 0x7FFFu + ((u >> 16) & 1u);
    return (unsigned short)(u >> 16);
}
__device__ __forceinline__ float bf2f(unsigned short h) {
    return __uint_as_float(((unsigned int)h) << 16);
}
__device__ __forceinline__ void async16(const ushort_t* g, ushort_t* l) {
    __builtin_amdgcn_global_load_lds(
        (const __attribute__((address_space(1))) unsigned int*)(g),
        (__attribute__((address_space(3))) unsigned int*)(l),
        16, 0, 0);
}

// ---------------- Kernel 0a: Xs[m][0:768]=hi(x), [768:1536]=lo(x) ----------------
__global__ __launch_bounds__(256) void split_x(const float* __restrict__ x,
                                               ushort_t* __restrict__ Xs)
{
    int idx = blockIdx.x * 256 + threadIdx.x;     // 8192*768/4 quads
    int row = idx / 192;
    int col = (idx - row * 192) * 4;
    float4 v = *reinterpret_cast<const float4*>(&x[(size_t)row * C_ + col]);
    unsigned short h0 = f2bf(v.x), h1 = f2bf(v.y), h2 = f2bf(v.z), h3 = f2bf(v.w);
    short4v hv = {(short)h0, (short)h1, (short)h2, (short)h3};
    short4v lv = {(short)f2bf(v.x - bf2f(h0)), (short)f2bf(v.y - bf2f(h1)),
                  (short)f2bf(v.z - bf2f(h2)), (short)f2bf(v.w - bf2f(h3))};
    *reinterpret_cast<short4v*>(&Xs[(size_t)row * KSPLIT + col]) = hv;
    *reinterpret_cast<short4v*>(&Xs[(size_t)row * KSPLIT + 768 + col]) = lv;
}

// ---------------- Kernel 0b: Ws[n][0:768]=hi(W[k][n]) , [768:1536]=lo ----------------
__global__ __launch_bounds__(256) void split_w(const float* __restrict__ W,
                                               ushort_t* __restrict__ Ws)
{
    __shared__ float tile[64][65];
    int n0 = blockIdx.x * 64, k0 = blockIdx.y * 64;
    int tid = threadIdx.x;
    #pragma unroll
    for (int t = 0; t < 16; ++t) {
        int c = t * 256 + tid;
        int kr = c >> 6, nc = c & 63;
        tile[kr][nc] = W[(size_t)(k0 + kr) * N3C + n0 + nc];
    }
    __syncthreads();
    #pragma unroll
    for (int t = 0; t < 16; ++t) {
        int c = t * 256 + tid;
        int nr = c >> 6, kc = c & 63;
        float v = tile[kc][nr];
        unsigned short h = f2bf(v);
        Ws[(size_t)(n0 + nr) * KSPLIT + k0 + kc] = h;
        Ws[(size_t)(n0 + nr) * KSPLIT + 768 + k0 + kc] = f2bf(v - bf2f(h));
    }
}

// ---------------- Kernel 1: qkv GEMM, plain bf16 MFMA over concatenated K ----------------
__global__ __launch_bounds__(256) void qkv_gemm(const ushort_t* __restrict__ Xs,
                                                const ushort_t* __restrict__ Ws,
                                                const float* __restrict__ bias,
                                                ushort_t* __restrict__ Qh,
                                                ushort_t* __restrict__ Ql,
                                                ushort_t* __restrict__ Kh,
                                                ushort_t* __restrict__ Kl,
                                                ushort_t* __restrict__ Vt)
{
    __shared__ __align__(16) ushort_t As[128 * 64];   // [m][k] linear (global_load_lds)
    __shared__ __align__(16) ushort_t Bs[128 * 64];   // [n][k] linear

    int tid = threadIdx.x, lane = tid & 63, w = tid >> 6;
    int wm = w >> 1, wn = w & 1;
    int l15 = lane & 15, l4 = lane >> 4;
    int lrow = lane >> 3, lcol = (lane & 7) * 8;

    int wg = blockIdx.x;
    int l = (wg & 7) * 144 + (wg >> 3);
    int mt = l / 18, nt = l % 18;
    int row0 = mt * 128, col0 = nt * 128;
    int kmax = (col0 >= 1536) ? 768 : 2304;

    f32x4 acc[4][4];
    #pragma unroll
    for (int i = 0; i < 4; ++i)
        #pragma unroll
        for (int j = 0; j < 4; ++j)
            acc[i][j] = f32x4{0.f, 0.f, 0.f, 0.f};

    for (int k0 = 0; k0 < kmax; k0 += 64) {
        int ka = (k0 < 1536) ? k0 : k0 - 1536;
        int kb = (k0 < 768) ? k0 : k0 - 768;
        __syncthreads();
        const ushort_t* gA = Xs + (size_t)(row0 + w * 32 + lrow) * KSPLIT + ka + lcol;
        const ushort_t* gB = Ws + (size_t)(col0 + w * 32 + lrow) * KSPLIT + kb + lcol;
        #pragma unroll
        for (int j = 0; j < 4; ++j) {
            async16(gA + (size_t)j * 8 * KSPLIT, &As[(w * 32 + j * 8) * 64]);
            async16(gB + (size_t)j * 8 * KSPLIT, &Bs[(w * 32 + j * 8) * 64]);
        }
        __syncthreads();

        #pragma unroll
        for (int kk = 0; kk < 2; ++kk) {
            bf16x8 af[4], bfr[4];
            #pragma unroll
            for (int m = 0; m < 4; ++m)
                af[m] = *reinterpret_cast<const bf16x8*>(&As[(wm * 64 + m * 16 + l15) * 64 + kk * 32 + l4 * 8]);
            #pragma unroll
            for (int n = 0; n < 4; ++n)
                bfr[n] = *reinterpret_cast<const bf16x8*>(&Bs[(wn * 64 + n * 16 + l15) * 64 + kk * 32 + l4 * 8]);
            #pragma unroll
            for (int m = 0; m < 4; ++m)
                #pragma unroll
                for (int n = 0; n < 4; ++n)
                    acc[m][n] = __builtin_amdgcn_mfma_f32_16x16x32_bf16(af[m], bfr[n], acc[m][n], 0, 0, 0);
        }
    }

    #pragma unroll
    for (int n = 0; n < 4; ++n) {
        int gcol = col0 + wn * 64 + n * 16 + l15;
        int p    = gcol / C_;
        int rem  = gcol - p * C_;
        int h    = rem >> 6, d = rem & 63;
        float bv = bias[gcol];
        #pragma unroll
        for (int m = 0; m < 4; ++m) {
            #pragma unroll
            for (int r = 0; r < 4; ++r) {
                int grow = row0 + wm * 64 + m * 16 + l4 * 4 + r;
                int b = grow >> 11, t = grow & (T_ - 1);
                int bh = b * H_ + h;
                float v = acc[m][n][r] + bv;
                if (p == 0) {
                    float v8 = v * QSCALE;          // sqrt(d) * log2(e) folded into Q
                    unsigned short hi = f2bf(v8);
                    size_t idx = ((size_t)bh * T_ + t) * D_ + d;
                    Qh[idx] = hi;
                    Ql[idx] = f2bf(v8 - bf2f(hi));
                } else if (p == 1) {
                    unsigned short hi = f2bf(v);
                    size_t idx = ((size_t)bh * T_ + t) * D_ + d;
                    Kh[idx] = hi;
                    Kl[idx] = f2bf(v - bf2f(hi));
                } else {
                    Vt[((size_t)bh * D_ + d) * T_ + t] = f2bf(v);  // transposed store
                }
            }
        }
    }
}

// ---------------- Kernel 2: flash attention, swapped-operand MFMA ----------------
// Block: 4 waves x 32 q-rows (2 subtiles of 16) = 128 q-rows. KV tile = 64 keys,
// double-buffered via global_load_lds with pre-swizzled source (XOR bank swizzle).
// S' = mfma(K,Q): lane owns q=l15, 16 k values -> in-lane softmax, 2 shfl per reduce.
// PV swapped: Y'[d][q] = mfma(V,P) so rescale by per-lane sc applies directly.
__global__ __launch_bounds__(256) void attn(const ushort_t* __restrict__ Qh,
                                            const ushort_t* __restrict__ Ql,
                                            const ushort_t* __restrict__ Kh,
                                            const ushort_t* __restrict__ Kl,
                                            const ushort_t* __restrict__ Vt,
                                            float* __restrict__ out)
{
    // layout (shorts): buf0 KH[4096] KL[4096] VS[4096] | buf1 same | Ps 4*16*PPS
    __shared__ __align__(16) char smem[58368];
    ushort_t* lds = (ushort_t*)smem;

    int tid = threadIdx.x, lane = tid & 63, w = tid >> 6;
    int l15 = lane & 15, l4 = lane >> 4;
    int bid = blockIdx.x;
    int qt = 15 - bid / BH_;              // longest q-blocks scheduled first
    int bh = bid % BH_;
    int b = bh / H_, h = bh % H_;
    int q0 = qt * 128;
    int ntile = 2 * qt + 2;

    // Q fragments (B-operand: j=q on l15, k-slice on l4*8), 2 subtiles, hi/lo
    bf16x8 qfh[2][2], qfl[2][2];
    #pragma unroll
    for (int qs = 0; qs < 2; ++qs) {
        int q = q0 + w * 32 + qs * 16 + l15;
        const ushort_t* ph = Qh + ((size_t)bh * T_ + q) * D_;
        const ushort_t* pl = Ql + ((size_t)bh * T_ + q) * D_;
        qfh[qs][0] = *reinterpret_cast<const bf16x8*>(ph + l4 * 8);
        qfh[qs][1] = *reinterpret_cast<const bf16x8*>(ph + 32 + l4 * 8);
        qfl[qs][0] = *reinterpret_cast<const bf16x8*>(pl + l4 * 8);
        qfl[qs][1] = *reinterpret_cast<const bf16x8*>(pl + 32 + l4 * 8);
    }

    f32x4 yacc[2][4];                     // Y'[d][q]: d = dt*16+l4*4+r, q = l15
    #pragma unroll
    for (int qs = 0; qs < 2; ++qs)
        #pragma unroll
        for (int dt = 0; dt < 4; ++dt)
            yacc[qs][dt] = f32x4{0.f, 0.f, 0.f, 0.f};
    float m_run[2] = {-INFINITY, -INFINITY};
    float l_run[2] = {0.f, 0.f};

    // staging: linear LDS dest (wave-uniform base + lane*16B), source col XORed
    int srow = lane >> 3;                           // row within 8-row chunk
    int scol = ((lane & 7) ^ srow) << 3;            // pre-swizzled source col (shorts)
    ushort_t* Pw = lds + 24576 + w * (16 * PPS);
    const size_t kbase = (size_t)bh * T_;
    const size_t vbase = (size_t)bh * D_;

    // prologue: stage tile 0 into buf 0
    #pragma unroll
    for (int j = 0; j < 2; ++j) {
        int row = (w * 2 + j) * 8 + srow;
        ushort_t* dK = lds + (w * 2 + j) * 512;
        async16(Kh + (kbase + row) * D_ + scol, dK);
        async16(Kl + (kbase + row) * D_ + scol, dK + 4096);
        async16(Vt + (vbase + row) * T_ + scol, dK + 8192);
    }
    __syncthreads();

    int cur = 0;
    for (int it = 0; it < ntile; ++it) {
        int k0 = it * 64;
        int nxt = cur ^ 1;
        if (it + 1 < ntile) {                       // prefetch next tile
            int k0n = k0 + 64;
            #pragma unroll
            for (int j = 0; j < 2; ++j) {
                int row = (w * 2 + j) * 8 + srow;
                ushort_t* dK = lds + nxt * 12288 + (w * 2 + j) * 512;
                async16(Kh + (kbase + k0n + row) * D_ + scol, dK);
                async16(Kl + (kbase + k0n + row) * D_ + scol, dK + 4096);
                async16(Vt + (vbase + row) * T_ + k0n + scol, dK + 8192);
            }
        }

        if (k0 <= q0 + w * 32 + 31) {               // skip fully-masked wave-tiles
            const char* KHc = (const char*)(lds + cur * 12288);
            const char* KLc = KHc + 8192;
            const char* VSc = KHc + 16384;
            bf16x8 pa[2][2];

            #pragma unroll
            for (int qs = 0; qs < 2; ++qs) {
                f32x4 sa[4];
                #pragma unroll
                for (int i = 0; i < 4; ++i) sa[i] = f32x4{0.f, 0.f, 0.f, 0.f};

                __builtin_amdgcn_s_setprio(1);
                #pragma unroll
                for (int kt = 0; kt < 4; ++kt) {
                    int krow = kt * 16 + l15;
                    int swz = (krow & 7) << 4;
                    #pragma unroll
                    for (int dh = 0; dh < 2; ++dh) {
                        int off = krow * 128 + ((dh * 64 + l4 * 16) ^ swz);
                        bf16x8 kfh = *reinterpret_cast<const bf16x8*>(KHc + off);
                        bf16x8 kfl = *reinterpret_cast<const bf16x8*>(KLc + off);
                        sa[kt] = __builtin_amdgcn_mfma_f32_16x16x32_bf16(kfh, qfh[qs][dh], sa[kt], 0, 0, 0);
                        sa[kt] = __builtin_amdgcn_mfma_f32_16x16x32_bf16(kfl, qfh[qs][dh], sa[kt], 0, 0, 0);
                        sa[kt] = __builtin_amdgcn_mfma_f32_16x16x32_bf16(kfh, qfl[qs][dh], sa[kt], 0, 0, 0);
                    }
                }
                __builtin_amdgcn_s_setprio(0);

                if (it >= ntile - 2) {              // diagonal tiles: causal mask
                    int qg = q0 + w * 32 + qs * 16 + l15;
                    #pragma unroll
                    for (int kt = 0; kt < 4; ++kt)
                        #pragma unroll
                        for (int r = 0; r < 4; ++r)
                            if (k0 + kt * 16 + l4 * 4 + r > qg) sa[kt][r] = -INFINITY;
                }

                // online softmax (log2 domain), q per-lane
                float mx = sa[0][0];
                #pragma unroll
                for (int kt = 0; kt < 4; ++kt)
                    #pragma unroll
                    for (int r = 0; r < 4; ++r) mx = fmaxf(mx, sa[kt][r]);
                mx = fmaxf(mx, __shfl_xor(mx, 16));
                mx = fmaxf(mx, __shfl_xor(mx, 32));

                float mn;
                if (__all(mx <= m_run[qs] + 8.0f)) {   // defer-max (p bounded by 2^8)
                    mn = m_run[qs];
                } else {
                    mn = fmaxf(m_run[qs], mx);
                    float sc = exp2f(m_run[qs] - mn);
                    m_run[qs] = mn;
                    l_run[qs] *= sc;
                    #pragma unroll
                    for (int dt = 0; dt < 4; ++dt) yacc[qs][dt] *= sc;
                }

                float p[4][4];
                float rs = 0.f;
                #pragma unroll
                for (int kt = 0; kt < 4; ++kt)
                    #pragma unroll
                    for (int r = 0; r < 4; ++r) {
                        p[kt][r] = exp2f(sa[kt][r] - mn);
                        rs += p[kt][r];
                    }
                rs += __shfl_xor(rs, 16);
                rs += __shfl_xor(rs, 32);
                l_run[qs] += rs;

                // pack P -> per-wave LDS (8 dword writes), read back as A..B-frag
                int pb = l15 * PPS + l4 * 4;
                #pragma unroll
                for (int kt = 0; kt < 4; ++kt) {
                    unsigned pw0, pw1;
                    asm volatile("v_cvt_pk_bf16_f32 %0, %1, %2" : "=v"(pw0) : "v"(p[kt][0]), "v"(p[kt][1]));
                    asm volatile("v_cvt_pk_bf16_f32 %0, %1, %2" : "=v"(pw1) : "v"(p[kt][2]), "v"(p[kt][3]));
                    *reinterpret_cast<unsigned*>(Pw + pb + kt * 16) = pw0;
                    *reinterpret_cast<unsigned*>(Pw + pb + kt * 16 + 2) = pw1;
                }
                pa[qs][0] = *reinterpret_cast<const bf16x8*>(Pw + l15 * PPS + l4 * 8);
                pa[qs][1] = *reinterpret_cast<const bf16x8*>(Pw + l15 * PPS + 32 + l4 * 8);
            }

            // PV: V frags read once, used for both q-subtiles
            __builtin_amdgcn_s_setprio(1);
            #pragma unroll
            for (int dt = 0; dt < 4; ++dt) {
                int vrow = dt * 16 + l15;
                int vswz = (vrow & 7) << 4;
                #pragma unroll
                for (int kk = 0; kk < 2; ++kk) {
                    bf16x8 vf = *reinterpret_cast<const bf16x8*>(VSc + vrow * 128 + ((kk * 64 + l4 * 16) ^ vswz));
                    yacc[0][dt] = __builtin_amdgcn_mfma_f32_16x16x32_bf16(vf, pa[0][kk], yacc[0][dt], 0, 0, 0);
                    yacc[1][dt] = __builtin_amdgcn_mfma_f32_16x16x32_bf16(vf, pa[1][kk], yacc[1][dt], 0, 0, 0);
                }
            }
            __builtin_amdgcn_s_setprio(0);
        }
        __syncthreads();                  // drains prefetch vmcnt + protects buffers
        cur = nxt;
    }

    // epilogue: transpose Y'[d][q] -> [q][d] via LDS, coalesced float4 stores
    float* ot = (float*)smem;             // [128][68]
    #pragma unroll
    for (int qs = 0; qs < 2; ++qs) {
        float inv = 1.0f / l_run[qs];
        int rq = w * 32 + qs * 16 + l15;
        #pragma unroll
        for (int dt = 0; dt < 4; ++dt)
            #pragma unroll
            for (int r = 0; r < 4; ++r)
                ot[rq * 68 + dt * 16 + l4 * 4 + r] = yacc[qs][dt][r] * inv;
    }
    __syncthreads();
    int rr = tid >> 1, c0 = (tid & 1) * 32;
    size_t ob = ((size_t)(b * T_ + q0 + rr)) * C_ + h * D_ + c0;
    #pragma unroll
    for (int u = 0; u < 8; ++u) {
        float4 v = *reinterpret_cast<const float4*>(&ot[rr * 68 + c0 + u * 4]);
        *reinterpret_cast<float4*>(&out[ob + u * 4]) = v;
    }
}

extern "C" void kernel_launch(void* const* d_in, const int* in_sizes, int n_in,
                              void* d_out, int out_size, void* d_ws, size_t ws_size,
                              hipStream_t stream)
{
    const float* x    = (const float*)d_in[0];
    const float* W    = (const float*)d_in[1];
    const float* bias = (const float*)d_in[2];

    const size_t per = (size_t)BH_ * T_ * D_;       // 6291456
    ushort_t* Qh = (ushort_t*)d_ws;
    ushort_t* Ql = Qh + per;
    ushort_t* Kh = Ql + per;
    ushort_t* Kl = Kh + per;
    ushort_t* Vt = Kl + per;
    ushort_t* Xs = Vt + per;                        // 8192*1536
    ushort_t* Ws = Xs + (size_t)8192 * KSPLIT;      // 2304*1536

    split_x<<<dim3((8192 * 768 / 4) / 256), 256, 0, stream>>>(x, Xs);
    split_w<<<dim3(N3C / 64, C_ / 64), 256, 0, stream>>>(W, Ws);
    qkv_gemm<<<dim3(64 * 18), 256, 0, stream>>>(Xs, Ws, bias, Qh, Ql, Kh, Kl, Vt);
    attn<<<dim3(BH_ * (T_ / 128)), 256, 0, stream>>>(Qh, Ql, Kh, Kl, Vt, (float*)d_out);
}

// Round 6
// 149.782 us; speedup vs baseline: 31.8722x; 1.5409x over previous
//
#include <hip/hip_runtime.h>
#include <math.h>

#define B_ 4
#define T_ 2048
#define C_ 768
#define H_ 12
#define D_ 64
#define N3C (3*C_)
#define BH_ (B_*H_)
#define QSCALE 11.5415603f   // 8 * log2(e): fold sqrt(d) and exp->exp2 into Q
#define PPS 72               // P-tile LDS pitch (shorts)

typedef float f32x4 __attribute__((ext_vector_type(4)));
typedef _Float16 f16x8 __attribute__((ext_vector_type(8)));
typedef unsigned short ushort_t;

__device__ __forceinline__ void async16(const void* g, void* l) {
    __builtin_amdgcn_global_load_lds(
        (const __attribute__((address_space(1))) unsigned int*)(g),
        (__attribute__((address_space(3))) unsigned int*)(l),
        16, 0, 0);
}

__device__ __forceinline__ unsigned pk_f16(float a, float b) {
    __fp16 r2[2];
    *(__fp16 __attribute__((ext_vector_type(2)))*)r2 = __builtin_amdgcn_cvt_pkrtz(a, b);
    return *(unsigned*)r2;
}

// ---------------- Kernel 0a: Xh = fp16(x) ----------------
__global__ __launch_bounds__(256) void conv_x(const float* __restrict__ x,
                                              _Float16* __restrict__ Xh)
{
    int idx = blockIdx.x * 256 + threadIdx.x;        // 8192*768/8 octs
    const float4 a = *reinterpret_cast<const float4*>(&x[(size_t)idx * 8]);
    const float4 b = *reinterpret_cast<const float4*>(&x[(size_t)idx * 8 + 4]);
    f16x8 o = {(_Float16)a.x, (_Float16)a.y, (_Float16)a.z, (_Float16)a.w,
               (_Float16)b.x, (_Float16)b.y, (_Float16)b.z, (_Float16)b.w};
    *reinterpret_cast<f16x8*>(&Xh[(size_t)idx * 8]) = o;
}

// ---------------- Kernel 0b: Wh[n][k] = fp16(W[k][n]) ----------------
__global__ __launch_bounds__(256) void conv_w(const float* __restrict__ W,
                                              _Float16* __restrict__ Wh)
{
    __shared__ float tile[64][65];
    int n0 = blockIdx.x * 64, k0 = blockIdx.y * 64;
    int tid = threadIdx.x;
    #pragma unroll
    for (int t = 0; t < 16; ++t) {
        int c = t * 256 + tid;
        int kr = c >> 6, nc = c & 63;
        tile[kr][nc] = W[(size_t)(k0 + kr) * N3C + n0 + nc];
    }
    __syncthreads();
    #pragma unroll
    for (int t = 0; t < 16; ++t) {
        int c = t * 256 + tid;
        int nr = c >> 6, kc = c & 63;
        Wh[(size_t)(n0 + nr) * C_ + k0 + kc] = (_Float16)tile[kc][nr];
    }
}

// ---------------- Kernel 1: qkv GEMM, fp16 MFMA, K=768 ----------------
// 128x128 tile, BK=64, 4 waves (2x2), global_load_lds with pre-swizzled source.
__global__ __launch_bounds__(256) void qkv_gemm(const _Float16* __restrict__ Xh,
                                                const _Float16* __restrict__ Wh,
                                                const float* __restrict__ bias,
                                                _Float16* __restrict__ Qf,
                                                _Float16* __restrict__ Kf,
                                                _Float16* __restrict__ Vt)
{
    __shared__ __align__(16) ushort_t As[128 * 64];   // [m][k], XOR-swizzled
    __shared__ __align__(16) ushort_t Bs[128 * 64];   // [n][k], XOR-swizzled

    int tid = threadIdx.x, lane = tid & 63, w = tid >> 6;
    int wm = w >> 1, wn = w & 1;
    int l15 = lane & 15, l4 = lane >> 4;
    int srow = lane >> 3;
    int scol = (((lane & 7) ^ srow)) << 3;            // pre-swizzled source col (halves)

    // XCD-chunked bijective swizzle (nwg=1152 % 8 == 0)
    int wg = blockIdx.x;
    int l = (wg & 7) * 144 + (wg >> 3);
    int mt = l / 18, nt = l % 18;
    int row0 = mt * 128, col0 = nt * 128;

    f32x4 acc[4][4];
    #pragma unroll
    for (int i = 0; i < 4; ++i)
        #pragma unroll
        for (int j = 0; j < 4; ++j)
            acc[i][j] = f32x4{0.f, 0.f, 0.f, 0.f};

    const char* AsC = (const char*)As;
    const char* BsC = (const char*)Bs;

    for (int k0 = 0; k0 < C_; k0 += 64) {
        __syncthreads();
        #pragma unroll
        for (int j = 0; j < 4; ++j) {
            int rowb = w * 32 + j * 8;
            async16(Xh + (size_t)(row0 + rowb + srow) * C_ + k0 + scol, &As[rowb * 64]);
            async16(Wh + (size_t)(col0 + rowb + srow) * C_ + k0 + scol, &Bs[rowb * 64]);
        }
        __syncthreads();

        #pragma unroll
        for (int kk = 0; kk < 2; ++kk) {
            f16x8 af[4], bfr[4];
            #pragma unroll
            for (int m = 0; m < 4; ++m) {
                int r = wm * 64 + m * 16 + l15;
                af[m] = *reinterpret_cast<const f16x8*>(AsC + r * 128 + ((kk * 64 + l4 * 16) ^ ((r & 7) << 4)));
            }
            #pragma unroll
            for (int n = 0; n < 4; ++n) {
                int r = wn * 64 + n * 16 + l15;
                bfr[n] = *reinterpret_cast<const f16x8*>(BsC + r * 128 + ((kk * 64 + l4 * 16) ^ ((r & 7) << 4)));
            }
            #pragma unroll
            for (int m = 0; m < 4; ++m)
                #pragma unroll
                for (int n = 0; n < 4; ++n)
                    acc[m][n] = __builtin_amdgcn_mfma_f32_16x16x32_f16(af[m], bfr[n], acc[m][n], 0, 0, 0);
        }
    }

    // epilogue: col = l15 (n), row = l4*4 + r (m)
    #pragma unroll
    for (int n = 0; n < 4; ++n) {
        int gcol = col0 + wn * 64 + n * 16 + l15;
        int p    = gcol / C_;
        int rem  = gcol - p * C_;
        int h    = rem >> 6, d = rem & 63;
        float bv = bias[gcol];
        #pragma unroll
        for (int m = 0; m < 4; ++m) {
            #pragma unroll
            for (int r = 0; r < 4; ++r) {
                int grow = row0 + wm * 64 + m * 16 + l4 * 4 + r;
                int b = grow >> 11, t = grow & (T_ - 1);
                int bh = b * H_ + h;
                float v = acc[m][n][r] + bv;
                if (p == 0) {
                    Qf[((size_t)bh * T_ + t) * D_ + d] = (_Float16)(v * QSCALE);
                } else if (p == 1) {
                    Kf[((size_t)bh * T_ + t) * D_ + d] = (_Float16)v;
                } else {
                    Vt[((size_t)bh * D_ + d) * T_ + t] = (_Float16)v;   // transposed
                }
            }
        }
    }
}

// ---------------- Kernel 2: flash attention, swapped-operand fp16 MFMA ----------------
// Block: 4 waves x 32 q-rows = 128 q-rows. KV tile = 64 keys, double-buffered
// global_load_lds with pre-swizzled source. S' = mfma(K,Q): lane owns q=l15;
// softmax in-lane (2 shfl per reduce). PV swapped: Y'[d][q] = mfma(V,P).
__global__ __launch_bounds__(256) void attn(const _Float16* __restrict__ Qf,
                                            const _Float16* __restrict__ Kf,
                                            const _Float16* __restrict__ Vt,
                                            float* __restrict__ out)
{
    // shorts layout: buf0 K[4096] V[4096] | buf1 K V | Ps 4*16*PPS  (41984 B)
    __shared__ __align__(16) char smem[41984];
    ushort_t* lds = (ushort_t*)smem;

    int tid = threadIdx.x, lane = tid & 63, w = tid >> 6;
    int l15 = lane & 15, l4 = lane >> 4;
    int bid = blockIdx.x;
    int qt = 15 - bid / BH_;              // longest q-blocks scheduled first
    int bh = bid % BH_;
    int b = bh / H_, h = bh % H_;
    int q0 = qt * 128;
    int ntile = 2 * qt + 2;

    // Q fragments (B-operand: q on l15, k-slice on l4*8), 2 subtiles
    f16x8 qf[2][2];
    #pragma unroll
    for (int qs = 0; qs < 2; ++qs) {
        int q = q0 + w * 32 + qs * 16 + l15;
        const _Float16* ph = Qf + ((size_t)bh * T_ + q) * D_;
        qf[qs][0] = *reinterpret_cast<const f16x8*>(ph + l4 * 8);
        qf[qs][1] = *reinterpret_cast<const f16x8*>(ph + 32 + l4 * 8);
    }

    f32x4 yacc[2][4];                     // Y'[d][q]: d = dt*16+l4*4+r, q = l15
    #pragma unroll
    for (int qs = 0; qs < 2; ++qs)
        #pragma unroll
        for (int dt = 0; dt < 4; ++dt)
            yacc[qs][dt] = f32x4{0.f, 0.f, 0.f, 0.f};
    float m_run[2] = {-INFINITY, -INFINITY};
    float l_run[2] = {0.f, 0.f};

    int srow = lane >> 3;
    int scol = ((lane & 7) ^ srow) << 3;             // pre-swizzled source col
    ushort_t* Pw = lds + 16384 + w * (16 * PPS);
    const size_t kbase = (size_t)bh * T_;
    const size_t vbase = (size_t)bh * D_;

    // prologue: stage tile 0 into buf 0
    #pragma unroll
    for (int j = 0; j < 2; ++j) {
        int row = (w * 2 + j) * 8 + srow;
        ushort_t* dK = lds + (w * 2 + j) * 512;
        async16(Kf + (kbase + row) * D_ + scol, dK);
        async16(Vt + (vbase + row) * T_ + scol, dK + 4096);
    }
    __syncthreads();

    int cur = 0;
    for (int it = 0; it < ntile; ++it) {
        int k0 = it * 64;
        int nxt = cur ^ 1;
        if (it + 1 < ntile) {                        // prefetch next tile
            int k0n = k0 + 64;
            #pragma unroll
            for (int j = 0; j < 2; ++j) {
                int row = (w * 2 + j) * 8 + srow;
                ushort_t* dK = lds + nxt * 8192 + (w * 2 + j) * 512;
                async16(Kf + (kbase + k0n + row) * D_ + scol, dK);
                async16(Vt + (vbase + row) * T_ + k0n + scol, dK + 4096);
            }
        }

        if (k0 <= q0 + w * 32 + 31) {                // skip fully-masked wave-tiles
            const char* KHc = (const char*)(lds + cur * 8192);
            const char* VSc = KHc + 8192;
            f16x8 pa[2][2];

            #pragma unroll
            for (int qs = 0; qs < 2; ++qs) {
                f32x4 sa[4];
                #pragma unroll
                for (int i = 0; i < 4; ++i) sa[i] = f32x4{0.f, 0.f, 0.f, 0.f};

                __builtin_amdgcn_s_setprio(1);
                #pragma unroll
                for (int kt = 0; kt < 4; ++kt) {
                    int krow = kt * 16 + l15;
                    int swz = (krow & 7) << 4;
                    #pragma unroll
                    for (int dh = 0; dh < 2; ++dh) {
                        f16x8 kf = *reinterpret_cast<const f16x8*>(KHc + krow * 128 + ((dh * 64 + l4 * 16) ^ swz));
                        sa[kt] = __builtin_amdgcn_mfma_f32_16x16x32_f16(kf, qf[qs][dh], sa[kt], 0, 0, 0);
                    }
                }
                __builtin_amdgcn_s_setprio(0);

                if (it >= ntile - 2) {               // diagonal tiles: causal mask
                    int qg = q0 + w * 32 + qs * 16 + l15;
                    #pragma unroll
                    for (int kt = 0; kt < 4; ++kt)
                        #pragma unroll
                        for (int r = 0; r < 4; ++r)
                            if (k0 + kt * 16 + l4 * 4 + r > qg) sa[kt][r] = -INFINITY;
                }

                // online softmax (log2 domain), q per-lane
                float mx = sa[0][0];
                #pragma unroll
                for (int kt = 0; kt < 4; ++kt)
                    #pragma unroll
                    for (int r = 0; r < 4; ++r) mx = fmaxf(mx, sa[kt][r]);
                mx = fmaxf(mx, __shfl_xor(mx, 16));
                mx = fmaxf(mx, __shfl_xor(mx, 32));

                float mn;
                if (__all(mx <= m_run[qs] + 8.0f)) {    // defer-max (p <= 2^8)
                    mn = m_run[qs];
                } else {
                    mn = fmaxf(m_run[qs], mx);
                    float sc = exp2f(m_run[qs] - mn);
                    m_run[qs] = mn;
                    l_run[qs] *= sc;
                    #pragma unroll
                    for (int dt = 0; dt < 4; ++dt) yacc[qs][dt] *= sc;
                }

                float p[4][4];
                float rs = 0.f;
                #pragma unroll
                for (int kt = 0; kt < 4; ++kt)
                    #pragma unroll
                    for (int r = 0; r < 4; ++r) {
                        p[kt][r] = exp2f(sa[kt][r] - mn);
                        rs += p[kt][r];
                    }
                rs += __shfl_xor(rs, 16);
                rs += __shfl_xor(rs, 32);
                l_run[qs] += rs;

                // pack P (fp16) -> per-wave LDS, read back as PV A/B fragment
                int pb = l15 * PPS + l4 * 4;
                #pragma unroll
                for (int kt = 0; kt < 4; ++kt) {
                    *reinterpret_cast<unsigned*>(Pw + pb + kt * 16) = pk_f16(p[kt][0], p[kt][1]);
                    *reinterpret_cast<unsigned*>(Pw + pb + kt * 16 + 2) = pk_f16(p[kt][2], p[kt][3]);
                }
                pa[qs][0] = *reinterpret_cast<const f16x8*>(Pw + l15 * PPS + l4 * 8);
                pa[qs][1] = *reinterpret_cast<const f16x8*>(Pw + l15 * PPS + 32 + l4 * 8);
            }

            // PV: V frags read once, used for both q-subtiles
            __builtin_amdgcn_s_setprio(1);
            #pragma unroll
            for (int dt = 0; dt < 4; ++dt) {
                int vrow = dt * 16 + l15;
                int vswz = (vrow & 7) << 4;
                #pragma unroll
                for (int kk = 0; kk < 2; ++kk) {
                    f16x8 vf = *reinterpret_cast<const f16x8*>(VSc + vrow * 128 + ((kk * 64 + l4 * 16) ^ vswz));
                    yacc[0][dt] = __builtin_amdgcn_mfma_f32_16x16x32_f16(vf, pa[0][kk], yacc[0][dt], 0, 0, 0);
                    yacc[1][dt] = __builtin_amdgcn_mfma_f32_16x16x32_f16(vf, pa[1][kk], yacc[1][dt], 0, 0, 0);
                }
            }
            __builtin_amdgcn_s_setprio(0);
        }
        __syncthreads();                  // drains prefetch vmcnt + protects buffers
        cur = nxt;
    }

    // epilogue: transpose Y'[d][q] -> [q][d] via LDS, coalesced float4 stores
    float* ot = (float*)smem;             // [128][68] = 34816 B
    #pragma unroll
    for (int qs = 0; qs < 2; ++qs) {
        float inv = 1.0f / l_run[qs];
        int rq = w * 32 + qs * 16 + l15;
        #pragma unroll
        for (int dt = 0; dt < 4; ++dt)
            #pragma unroll
            for (int r = 0; r < 4; ++r)
                ot[rq * 68 + dt * 16 + l4 * 4 + r] = yacc[qs][dt][r] * inv;
    }
    __syncthreads();
    int rr = tid >> 1, c0 = (tid & 1) * 32;
    size_t ob = ((size_t)(b * T_ + q0 + rr)) * C_ + h * D_ + c0;
    #pragma unroll
    for (int u = 0; u < 8; ++u) {
        float4 v = *reinterpret_cast<const float4*>(&ot[rr * 68 + c0 + u * 4]);
        *reinterpret_cast<float4*>(&out[ob + u * 4]) = v;
    }
}

extern "C" void kernel_launch(void* const* d_in, const int* in_sizes, int n_in,
                              void* d_out, int out_size, void* d_ws, size_t ws_size,
                              hipStream_t stream)
{
    const float* x    = (const float*)d_in[0];
    const float* W    = (const float*)d_in[1];
    const float* bias = (const float*)d_in[2];

    const size_t per = (size_t)BH_ * T_ * D_;       // 6291456
    _Float16* Qf = (_Float16*)d_ws;
    _Float16* Kf = Qf + per;
    _Float16* Vt = Kf + per;
    _Float16* Xh = Vt + per;                        // 8192*768
    _Float16* Wh = Xh + (size_t)8192 * C_;          // 2304*768
    // total ~54 MB of d_ws

    conv_x<<<dim3((8192 * 768 / 8) / 256), 256, 0, stream>>>(x, Xh);
    conv_w<<<dim3(N3C / 64, C_ / 64), 256, 0, stream>>>(W, Wh);
    qkv_gemm<<<dim3(64 * 18), 256, 0, stream>>>(Xh, Wh, bias, Qf, Kf, Vt);
    attn<<<dim3(BH_ * (T_ / 128)), 256, 0, stream>>>(Qf, Kf, Vt, (float*)d_out);
}